// Round 2
// baseline (812.757 us; speedup 1.0000x reference)
//
#include <hip/hip_runtime.h>
#include <cstdint>
#include <cstddef>

#define NN 8192
#define DIN 256
#define DHID 128
#define DOUT 64
#define MAXDEG 256

using short8  = __attribute__((ext_vector_type(8))) short;
using floatx4 = __attribute__((ext_vector_type(4))) float;

__device__ inline unsigned short f2bf(float x) {
  union { float f; unsigned u; } c; c.f = x;
  unsigned r = (c.u + 0x7FFFu + ((c.u >> 16) & 1u)) >> 16;   // RNE
  return (unsigned short)r;
}

// ---------------- GEMM1: Wh1 = feat[8192,256] @ W1[256,128] (fp32) ----------
// 32-row tiles -> 256 blocks (all CUs busy; was 128).
__global__ __launch_bounds__(256) void k_gemm1(const float* __restrict__ feat,
                                               const float* __restrict__ W1,
                                               float* __restrict__ Wh1) {
  __shared__ float Ws[64 * DHID];     // k-chunk x 128 cols (32 KB)
  __shared__ float Fs[32][65];        // 32 rows x 64 k (stride 65: conflict-free)
  const int tid = threadIdx.x;
  const int cx = tid & 31;            // cols cx*4..cx*4+3
  const int ry = tid >> 5;            // rows ry*4..ry*4+3
  const int r0 = blockIdx.x * 32;
  float acc[4][4] = {};
  for (int kc = 0; kc < DIN; kc += 64) {
    const float4* src = (const float4*)(W1 + (size_t)kc * DHID);
    float4* dst = (float4*)Ws;
    #pragma unroll
    for (int i = 0; i < 8; ++i) dst[i * 256 + tid] = src[i * 256 + tid];
    #pragma unroll
    for (int i = 0; i < 2; ++i) {
      int idx = i * 256 + tid;
      int row = idx >> 4, kq = idx & 15;
      float4 v = *(const float4*)(feat + (size_t)(r0 + row) * DIN + kc + kq * 4);
      Fs[row][kq * 4 + 0] = v.x; Fs[row][kq * 4 + 1] = v.y;
      Fs[row][kq * 4 + 2] = v.z; Fs[row][kq * 4 + 3] = v.w;
    }
    __syncthreads();
    #pragma unroll 4
    for (int k = 0; k < 64; ++k) {
      float4 w = *(const float4*)(Ws + k * DHID + cx * 4);
      #pragma unroll
      for (int r = 0; r < 4; ++r) {
        float f = Fs[ry * 4 + r][k];
        acc[r][0] += f * w.x; acc[r][1] += f * w.y;
        acc[r][2] += f * w.z; acc[r][3] += f * w.w;
      }
    }
    __syncthreads();
  }
  #pragma unroll
  for (int r = 0; r < 4; ++r) {
    float4 o = make_float4(acc[r][0], acc[r][1], acc[r][2], acc[r][3]);
    *(float4*)(Wh1 + (size_t)(r0 + ry * 4 + r) * DHID + cx * 4) = o;
  }
}

// ---------------- GEMM2: Wh2 = h1[8192,128] @ W2[128,64] (fp32) -------------
// 32-row tiles -> 256 blocks (was 64).
__global__ __launch_bounds__(256) void k_gemm2(const float* __restrict__ h1,
                                               const float* __restrict__ W2,
                                               float* __restrict__ Wh2) {
  __shared__ float Ws[64 * DOUT];     // 16 KB
  __shared__ float Fs[32][65];        // 8.3 KB
  const int tid = threadIdx.x;
  const int cx = tid & 15;            // cols cx*4
  const int ry = tid >> 4;            // rows ry*2 (0..15 -> 32 rows)
  const int r0 = blockIdx.x * 32;
  float acc[2][4] = {};
  for (int kc = 0; kc < DHID; kc += 64) {
    const float4* src = (const float4*)(W2 + (size_t)kc * DOUT);
    float4* dst = (float4*)Ws;
    #pragma unroll
    for (int i = 0; i < 4; ++i) dst[i * 256 + tid] = src[i * 256 + tid];
    #pragma unroll
    for (int i = 0; i < 2; ++i) {
      int idx = i * 256 + tid;
      int row = idx >> 4, kq = idx & 15;
      float4 v = *(const float4*)(h1 + (size_t)(r0 + row) * DHID + kc + kq * 4);
      Fs[row][kq * 4 + 0] = v.x; Fs[row][kq * 4 + 1] = v.y;
      Fs[row][kq * 4 + 2] = v.z; Fs[row][kq * 4 + 3] = v.w;
    }
    __syncthreads();
    #pragma unroll 4
    for (int k = 0; k < 64; ++k) {
      float4 w = *(const float4*)(Ws + k * DOUT + cx * 4);
      #pragma unroll
      for (int r = 0; r < 2; ++r) {
        float f = Fs[ry * 2 + r][k];
        acc[r][0] += f * w.x; acc[r][1] += f * w.y;
        acc[r][2] += f * w.z; acc[r][3] += f * w.w;
      }
    }
    __syncthreads();
  }
  #pragma unroll
  for (int r = 0; r < 2; ++r) {
    float4 o = make_float4(acc[r][0], acc[r][1], acc[r][2], acc[r][3]);
    *(float4*)(Wh2 + (size_t)(r0 + ry * 2 + r) * DOUT + cx * 4) = o;
  }
}

// ---------------- f1/f2 vectors ---------------------------------------------
__global__ __launch_bounds__(256) void k_fvec1(const float* __restrict__ Wh1,
                                               const float* __restrict__ a1,
                                               float* __restrict__ f1, float* __restrict__ f2) {
  int wv = threadIdx.x >> 6, lane = threadIdx.x & 63;
  int row = blockIdx.x * 4 + wv;
  float2 x = *(const float2*)(Wh1 + (size_t)row * DHID + lane * 2);
  float2 u = *(const float2*)(a1 + lane * 2);
  float2 v = *(const float2*)(a1 + DHID + lane * 2);
  float s1 = x.x * u.x + x.y * u.y;
  float s2 = x.x * v.x + x.y * v.y;
  #pragma unroll
  for (int off = 32; off; off >>= 1) { s1 += __shfl_down(s1, off); s2 += __shfl_down(s2, off); }
  if (lane == 0) { f1[row] = s1; f2[row] = s2; }
}

__global__ __launch_bounds__(256) void k_fvec2(const float* __restrict__ Wh2,
                                               const float* __restrict__ a2,
                                               float* __restrict__ f1, float* __restrict__ f2) {
  int wv = threadIdx.x >> 6, lane = threadIdx.x & 63;
  int row = blockIdx.x * 4 + wv;
  float x = Wh2[(size_t)row * DOUT + lane];
  float s1 = x * a2[lane];
  float s2 = x * a2[DOUT + lane];
  #pragma unroll
  for (int off = 32; off; off >>= 1) { s1 += __shfl_down(s1, off); s2 += __shfl_down(s2, off); }
  if (lane == 0) { f1[row] = s1; f2[row] = s2; }
}

// ---------------- Layer-1 attention: ONE WAVE PER ROW -----------------------
// 4 rows/block, waves fully independent -> 32 rows in flight per CU (was 8).
// 3 block barriers total; fill stores issued before softmax so their latency
// hides under it; per-wave vmcnt(0) (not a barrier) orders fill vs scatter.
__global__ __launch_bounds__(256) void k_att1(const float* __restrict__ adj,
                                              const float* __restrict__ f1v,
                                              const float* __restrict__ f2v,
                                              const float* __restrict__ Wh1,
                                              float* __restrict__ att_out,
                                              float* __restrict__ h1,
                                              int* __restrict__ csr,
                                              int* __restrict__ degree) {
  __shared__ int   scols[4][MAXDEG];
  __shared__ float sval[4][MAXDEG];
  __shared__ int   cnt[4];
  const int tid = threadIdx.x;
  const int wid = tid >> 6, lane = tid & 63;
  const int row = blockIdx.x * 4 + wid;
  if (lane == 0) cnt[wid] = 0;
  __syncthreads();
  // Phase A: scan this wave's adjacency row (32 x float4 per lane, coalesced)
  const float4* arow = (const float4*)(adj + (size_t)row * NN);
  #pragma unroll 4
  for (int it = 0; it < 32; ++it) {
    float4 v = arow[it * 64 + lane];
    int base = (it * 64 + lane) * 4;
    if (v.x > 0.0f) { int s = atomicAdd(&cnt[wid], 1); if (s < MAXDEG) scols[wid][s] = base; }
    if (v.y > 0.0f) { int s = atomicAdd(&cnt[wid], 1); if (s < MAXDEG) scols[wid][s] = base + 1; }
    if (v.z > 0.0f) { int s = atomicAdd(&cnt[wid], 1); if (s < MAXDEG) scols[wid][s] = base + 2; }
    if (v.w > 0.0f) { int s = atomicAdd(&cnt[wid], 1); if (s < MAXDEG) scols[wid][s] = base + 3; }
  }
  __syncthreads();                               // publish scols/cnt (cross-lane via LDS)
  const int deg = min(cnt[wid], MAXDEG);
  if (lane == 0) degree[row] = deg;
  // Dense fill issued NOW; completes while we do softmax below.
  const float fillv = (deg == 0) ? (1.0f / (float)NN) : 0.0f;
  float4 fv = make_float4(fillv, fillv, fillv, fillv);
  float4* orow = (float4*)(att_out + (size_t)row * NN);
  #pragma unroll 8
  for (int it = 0; it < 32; ++it) orow[it * 64 + lane] = fv;
  // CSR for layer 2
  for (int t = lane; t < deg; t += 64) csr[(size_t)row * MAXDEG + t] = scols[wid][t];
  // Phase B: softmax, up to 4 elements per lane, wave-wide shfl reductions
  const float f1r = f1v[row];
  float e[4]; int cols[4];
  float m = -3.0e38f;
  #pragma unroll
  for (int j = 0; j < 4; ++j) {
    int t = lane + j * 64;
    cols[j] = 0; e[j] = -3.0e38f;
    if (t < deg) {
      int c = scols[wid][t]; cols[j] = c;
      float x = f1r + f2v[c];
      e[j] = x > 0.0f ? x : 0.2f * x;
    }
    m = fmaxf(m, e[j]);
  }
  #pragma unroll
  for (int off = 32; off; off >>= 1) m = fmaxf(m, __shfl_xor(m, off));
  float ex[4]; float s = 0.0f;
  #pragma unroll
  for (int j = 0; j < 4; ++j) {
    ex[j] = __expf(e[j] - m);
    if (lane + j * 64 >= deg) ex[j] = 0.0f;
    s += ex[j];
  }
  #pragma unroll
  for (int off = 32; off; off >>= 1) s += __shfl_xor(s, off);
  const float inv = 1.0f / s;
  #pragma unroll
  for (int j = 0; j < 4; ++j) { int t = lane + j * 64; if (t < deg) sval[wid][t] = ex[j] * inv; }
  // Drain fill stores (wave-local; other waves keep running), then scatter own p's.
  asm volatile("s_waitcnt vmcnt(0)" ::: "memory");
  #pragma unroll
  for (int j = 0; j < 4; ++j) {
    int t = lane + j * 64;
    if (t < deg) att_out[(size_t)row * NN + cols[j]] = ex[j] * inv;
  }
  __syncthreads();                               // publish sval (cross-lane via LDS)
  // Phase E: hp = att_row @ Wh1 (sparse). One wave owns the whole 128-wide row.
  float2 acc = make_float2(0.0f, 0.0f);
  if (deg > 0) {
    #pragma unroll 4
    for (int t = 0; t < deg; ++t) {
      float sv = sval[wid][t];
      float2 w = *(const float2*)(Wh1 + (size_t)scols[wid][t] * DHID + lane * 2);
      acc.x += sv * w.x; acc.y += sv * w.y;
    }
  } else {
    for (int r = 0; r < NN; ++r) {
      float2 w = *(const float2*)(Wh1 + (size_t)r * DHID + lane * 2);
      acc.x += w.x; acc.y += w.y;
    }
    acc.x *= (1.0f / (float)NN); acc.y *= (1.0f / (float)NN);
  }
  float hx = acc.x > 0.0f ? acc.x : (__expf(acc.x) - 1.0f);
  float hy = acc.y > 0.0f ? acc.y : (__expf(acc.y) - 1.0f);
  *(float2*)(h1 + (size_t)row * DHID + lane * 2) = make_float2(hx, hy);
}

// ---------------- Layer-2 attention: ONE WAVE PER ROW (reuses CSR) ----------
__global__ __launch_bounds__(256) void k_att2(const int* __restrict__ csr,
                                              const int* __restrict__ degree,
                                              const float* __restrict__ f1v,
                                              const float* __restrict__ f2v,
                                              const float* __restrict__ Wh2,
                                              float* __restrict__ h2) {
  __shared__ int   scols[4][MAXDEG];
  __shared__ float sval[4][MAXDEG];
  const int tid = threadIdx.x;
  const int wid = tid >> 6, lane = tid & 63;
  const int row = blockIdx.x * 4 + wid;
  const int deg = degree[row];
  const float f1r = f1v[row];
  float e[4]; int cols[4];
  float m = -3.0e38f;
  #pragma unroll
  for (int j = 0; j < 4; ++j) {
    int t = lane + j * 64;
    cols[j] = 0; e[j] = -3.0e38f;
    if (t < deg) {
      int c = csr[(size_t)row * MAXDEG + t];
      cols[j] = c; scols[wid][t] = c;
      float x = f1r + f2v[c];
      e[j] = x > 0.0f ? x : 0.2f * x;
    }
    m = fmaxf(m, e[j]);
  }
  #pragma unroll
  for (int off = 32; off; off >>= 1) m = fmaxf(m, __shfl_xor(m, off));
  float ex[4]; float s = 0.0f;
  #pragma unroll
  for (int j = 0; j < 4; ++j) {
    ex[j] = __expf(e[j] - m);
    if (lane + j * 64 >= deg) ex[j] = 0.0f;
    s += ex[j];
  }
  #pragma unroll
  for (int off = 32; off; off >>= 1) s += __shfl_xor(s, off);
  const float inv = 1.0f / s;
  #pragma unroll
  for (int j = 0; j < 4; ++j) { int t = lane + j * 64; if (t < deg) sval[wid][t] = ex[j] * inv; }
  __syncthreads();                               // publish scols/sval
  float acc = 0.0f;
  if (deg > 0) {
    #pragma unroll 4
    for (int t = 0; t < deg; ++t)
      acc += sval[wid][t] * Wh2[(size_t)scols[wid][t] * DOUT + lane];
  } else {
    for (int r = 0; r < NN; ++r) acc += Wh2[(size_t)r * DOUT + lane];
    acc *= (1.0f / (float)NN);
  }
  h2[(size_t)row * DOUT + lane] = acc;
}

// ---------------- genenet: sigmoid(h2 @ h2^T) * rowmask (bf16 MFMA) ---------
// Staging/fragment swizzle unchanged. NEW epilogue: transpose accumulators
// through the (now dead) As/Bs LDS in two 64-row chunks, then store float4
// with 512-B-contiguous rows (was 64 scalar 4-B scattered stores/thread).
__global__ __launch_bounds__(256) void k_genenet(const float* __restrict__ h2,
                                                 const int* __restrict__ degree,
                                                 float* __restrict__ out) {
  __shared__ __align__(16) unsigned short AB[2 * 128 * 64];   // 32 KB: As | Bs, reused as stage
  __shared__ float dmask[128];
  unsigned short* As = AB;
  unsigned short* Bs = AB + 128 * 64;
  const int tid = threadIdx.x;
  const int R0 = blockIdx.x * 128, C0 = blockIdx.y * 128;
  #pragma unroll
  for (int it = 0; it < 8; ++it) {
    int idx = it * 256 + tid;
    int r = idx >> 4, kq = idx & 15;
    int c = kq >> 1, hf = kq & 1;
    int off = r * 64 + (((c + r) & 7) << 3) + (hf << 2);   // in shorts, 8B-aligned
    float4 va = *(const float4*)(h2 + (size_t)(R0 + r) * DOUT + kq * 4);
    float4 vb = *(const float4*)(h2 + (size_t)(C0 + r) * DOUT + kq * 4);
    ushort4 ba = make_ushort4(f2bf(va.x), f2bf(va.y), f2bf(va.z), f2bf(va.w));
    ushort4 bb = make_ushort4(f2bf(vb.x), f2bf(vb.y), f2bf(vb.z), f2bf(vb.w));
    *(ushort4*)&As[off] = ba;
    *(ushort4*)&Bs[off] = bb;
  }
  if (tid < 128) dmask[tid] = (degree[R0 + tid] > 0) ? 1.0f : 0.0f;
  __syncthreads();
  const int wave = tid >> 6, lane = tid & 63;
  const int wr = wave >> 1, wc = wave & 1;     // 2x2 waves over 128x128 tile
  const int lr = lane & 15, quad = lane >> 4;
  short8 a[4][2], b[4][2];
  #pragma unroll
  for (int mi = 0; mi < 4; ++mi) {
    int r = wr * 64 + mi * 16 + lr;
    #pragma unroll
    for (int j = 0; j < 2; ++j) {
      int c = quad + 4 * j;
      a[mi][j] = *(const short8*)(const void*)&As[r * 64 + (((c + r) & 7) << 3)];
    }
  }
  #pragma unroll
  for (int ni = 0; ni < 4; ++ni) {
    int r = wc * 64 + ni * 16 + lr;
    #pragma unroll
    for (int j = 0; j < 2; ++j) {
      int c = quad + 4 * j;
      b[ni][j] = *(const short8*)(const void*)&Bs[r * 64 + (((c + r) & 7) << 3)];
    }
  }
  floatx4 acc[4][4] = {};
  #pragma unroll
  for (int mi = 0; mi < 4; ++mi)
    #pragma unroll
    for (int ni = 0; ni < 4; ++ni) {
      acc[mi][ni] = __builtin_amdgcn_mfma_f32_16x16x32_bf16(a[mi][0], b[ni][0], acc[mi][ni], 0, 0, 0);
      acc[mi][ni] = __builtin_amdgcn_mfma_f32_16x16x32_bf16(a[mi][1], b[ni][1], acc[mi][ni], 0, 0, 0);
    }
  __syncthreads();                 // everyone done reading As/Bs; safe to reuse as stage
  float* stage = (float*)AB;       // 64 rows x 128 cols fp32 (32 KB)
  #pragma unroll
  for (int half = 0; half < 2; ++half) {
    if (wr == half) {              // waves owning rows [half*64, half*64+64)
      #pragma unroll
      for (int mi = 0; mi < 4; ++mi)
        #pragma unroll
        for (int reg = 0; reg < 4; ++reg) {
          int lrow = mi * 16 + quad * 4 + reg;          // 0..63 within half
          #pragma unroll
          for (int ni = 0; ni < 4; ++ni)
            stage[lrow * 128 + wc * 64 + ni * 16 + lr] = acc[mi][ni][reg];
        }
    }
    __syncthreads();
    #pragma unroll
    for (int it = 0; it < 8; ++it) {
      int idx = it * 256 + tid;    // 0..2047
      int r = idx >> 5, c4 = idx & 31;                  // 32 threads stream one row
      float4 x = *(const float4*)&stage[r * 128 + c4 * 4];
      float msk = dmask[half * 64 + r];
      float4 o;
      o.x = msk * __builtin_amdgcn_rcpf(1.0f + __expf(-x.x));
      o.y = msk * __builtin_amdgcn_rcpf(1.0f + __expf(-x.y));
      o.z = msk * __builtin_amdgcn_rcpf(1.0f + __expf(-x.z));
      o.w = msk * __builtin_amdgcn_rcpf(1.0f + __expf(-x.w));
      *(float4*)(out + (size_t)(R0 + half * 64 + r) * NN + C0 + c4 * 4) = o;
    }
    if (half == 0) __syncthreads();                     // before overwriting stage
  }
}

extern "C" void kernel_launch(void* const* d_in, const int* in_sizes, int n_in,
                              void* d_out, int out_size, void* d_ws, size_t ws_size,
                              hipStream_t stream) {
  const float* feat = (const float*)d_in[0];
  const float* adj  = (const float*)d_in[1];
  const float* W1   = (const float*)d_in[2];
  const float* a1   = (const float*)d_in[3];
  const float* W2   = (const float*)d_in[4];
  const float* a2   = (const float*)d_in[5];
  float* out = (float*)d_out;
  float* h2_out  = out;                               // [8192,64]
  float* gen_out = out + (size_t)NN * DOUT;           // [8192,8192]
  float* att_out = gen_out + (size_t)NN * NN;         // [8192,8192]
  // Big scratch lives inside gen_out: it is only written by the FINAL kernel,
  // and all readers of these intermediates run before it (stream-ordered).
  int*   csr  = (int*)gen_out;                        // 8192*256 ints (8 MB)
  float* Wh1  = gen_out + 2097152;                    // 4 MB
  float* h1   = gen_out + 3145728;                    // 4 MB
  float* Wh2  = gen_out + 4194304;                    // 2 MB
  float* f1_1 = gen_out + 4718592;
  float* f2_1 = f1_1 + NN;
  float* f1_2 = f2_1 + NN;
  float* f2_2 = f1_2 + NN;
  int* degree = (int*)d_ws;                           // 32 KB; survives to k_genenet

  k_gemm1  <<<dim3(NN / 32), dim3(256), 0, stream>>>(feat, W1, Wh1);
  k_fvec1  <<<dim3(NN / 4),  dim3(256), 0, stream>>>(Wh1, a1, f1_1, f2_1);
  k_att1   <<<dim3(NN / 4),  dim3(256), 0, stream>>>(adj, f1_1, f2_1, Wh1, att_out, h1, csr, degree);
  k_gemm2  <<<dim3(NN / 32), dim3(256), 0, stream>>>(h1, W2, Wh2);
  k_fvec2  <<<dim3(NN / 4),  dim3(256), 0, stream>>>(Wh2, a2, f1_2, f2_2);
  k_att2   <<<dim3(NN / 4),  dim3(256), 0, stream>>>(csr, degree, f1_2, f2_2, Wh2, h2_out);
  k_genenet<<<dim3(64, 64),  dim3(256), 0, stream>>>(h2_out, degree, gen_out);
}

// Round 4
// 798.378 us; speedup vs baseline: 1.0180x; 1.0180x over previous
//
#include <hip/hip_runtime.h>
#include <cstdint>
#include <cstddef>

#define NN 8192
#define DIN 256
#define DHID 128
#define DOUT 64
#define MAXDEG 256

using short8  = __attribute__((ext_vector_type(8))) short;
using floatx4 = __attribute__((ext_vector_type(4))) float;

__device__ inline unsigned short f2bf(float x) {
  union { float f; unsigned u; } c; c.f = x;
  unsigned r = (c.u + 0x7FFFu + ((c.u >> 16) & 1u)) >> 16;   // RNE
  return (unsigned short)r;
}

// ---------------- GEMM1: Wh1 = feat[8192,256] @ W1[256,128] (fp32) ----------
__global__ __launch_bounds__(256) void k_gemm1(const float* __restrict__ feat,
                                               const float* __restrict__ W1,
                                               float* __restrict__ Wh1) {
  __shared__ float Ws[64 * DHID];     // k-chunk x 128 cols (32 KB)
  __shared__ float Fs[32][65];        // 32 rows x 64 k (stride 65: conflict-free)
  const int tid = threadIdx.x;
  const int cx = tid & 31;            // cols cx*4..cx*4+3
  const int ry = tid >> 5;            // rows ry*4..ry*4+3
  const int r0 = blockIdx.x * 32;
  float acc[4][4] = {};
  for (int kc = 0; kc < DIN; kc += 64) {
    const float4* src = (const float4*)(W1 + (size_t)kc * DHID);
    float4* dst = (float4*)Ws;
    #pragma unroll
    for (int i = 0; i < 8; ++i) dst[i * 256 + tid] = src[i * 256 + tid];
    #pragma unroll
    for (int i = 0; i < 2; ++i) {
      int idx = i * 256 + tid;
      int row = idx >> 4, kq = idx & 15;
      float4 v = *(const float4*)(feat + (size_t)(r0 + row) * DIN + kc + kq * 4);
      Fs[row][kq * 4 + 0] = v.x; Fs[row][kq * 4 + 1] = v.y;
      Fs[row][kq * 4 + 2] = v.z; Fs[row][kq * 4 + 3] = v.w;
    }
    __syncthreads();
    #pragma unroll 4
    for (int k = 0; k < 64; ++k) {
      float4 w = *(const float4*)(Ws + k * DHID + cx * 4);
      #pragma unroll
      for (int r = 0; r < 4; ++r) {
        float f = Fs[ry * 4 + r][k];
        acc[r][0] += f * w.x; acc[r][1] += f * w.y;
        acc[r][2] += f * w.z; acc[r][3] += f * w.w;
      }
    }
    __syncthreads();
  }
  #pragma unroll
  for (int r = 0; r < 4; ++r) {
    float4 o = make_float4(acc[r][0], acc[r][1], acc[r][2], acc[r][3]);
    *(float4*)(Wh1 + (size_t)(r0 + ry * 4 + r) * DHID + cx * 4) = o;
  }
}

// ---------------- GEMM2: Wh2 = h1[8192,128] @ W2[128,64] (fp32) -------------
__global__ __launch_bounds__(256) void k_gemm2(const float* __restrict__ h1,
                                               const float* __restrict__ W2,
                                               float* __restrict__ Wh2) {
  __shared__ float Ws[64 * DOUT];     // 16 KB
  __shared__ float Fs[32][65];        // 8.3 KB
  const int tid = threadIdx.x;
  const int cx = tid & 15;            // cols cx*4
  const int ry = tid >> 4;            // rows ry*2 (0..15 -> 32 rows)
  const int r0 = blockIdx.x * 32;
  float acc[2][4] = {};
  for (int kc = 0; kc < DHID; kc += 64) {
    const float4* src = (const float4*)(W2 + (size_t)kc * DOUT);
    float4* dst = (float4*)Ws;
    #pragma unroll
    for (int i = 0; i < 4; ++i) dst[i * 256 + tid] = src[i * 256 + tid];
    #pragma unroll
    for (int i = 0; i < 2; ++i) {
      int idx = i * 256 + tid;
      int row = idx >> 4, kq = idx & 15;
      float4 v = *(const float4*)(h1 + (size_t)(r0 + row) * DHID + kc + kq * 4);
      Fs[row][kq * 4 + 0] = v.x; Fs[row][kq * 4 + 1] = v.y;
      Fs[row][kq * 4 + 2] = v.z; Fs[row][kq * 4 + 3] = v.w;
    }
    __syncthreads();
    #pragma unroll 4
    for (int k = 0; k < 64; ++k) {
      float4 w = *(const float4*)(Ws + k * DOUT + cx * 4);
      #pragma unroll
      for (int r = 0; r < 2; ++r) {
        float f = Fs[ry * 2 + r][k];
        acc[r][0] += f * w.x; acc[r][1] += f * w.y;
        acc[r][2] += f * w.z; acc[r][3] += f * w.w;
      }
    }
    __syncthreads();
  }
  #pragma unroll
  for (int r = 0; r < 2; ++r) {
    float4 o = make_float4(acc[r][0], acc[r][1], acc[r][2], acc[r][3]);
    *(float4*)(Wh2 + (size_t)(r0 + ry * 2 + r) * DOUT + cx * 4) = o;
  }
}

// ---------------- f1/f2 vectors ---------------------------------------------
__global__ __launch_bounds__(256) void k_fvec1(const float* __restrict__ Wh1,
                                               const float* __restrict__ a1,
                                               float* __restrict__ f1, float* __restrict__ f2) {
  int wv = threadIdx.x >> 6, lane = threadIdx.x & 63;
  int row = blockIdx.x * 4 + wv;
  float2 x = *(const float2*)(Wh1 + (size_t)row * DHID + lane * 2);
  float2 u = *(const float2*)(a1 + lane * 2);
  float2 v = *(const float2*)(a1 + DHID + lane * 2);
  float s1 = x.x * u.x + x.y * u.y;
  float s2 = x.x * v.x + x.y * v.y;
  #pragma unroll
  for (int off = 32; off; off >>= 1) { s1 += __shfl_down(s1, off); s2 += __shfl_down(s2, off); }
  if (lane == 0) { f1[row] = s1; f2[row] = s2; }
}

__global__ __launch_bounds__(256) void k_fvec2(const float* __restrict__ Wh2,
                                               const float* __restrict__ a2,
                                               float* __restrict__ f1, float* __restrict__ f2) {
  int wv = threadIdx.x >> 6, lane = threadIdx.x & 63;
  int row = blockIdx.x * 4 + wv;
  float x = Wh2[(size_t)row * DOUT + lane];
  float s1 = x * a2[lane];
  float s2 = x * a2[DOUT + lane];
  #pragma unroll
  for (int off = 32; off; off >>= 1) { s1 += __shfl_down(s1, off); s2 += __shfl_down(s2, off); }
  if (lane == 0) { f1[row] = s1; f2[row] = s2; }
}

// ---------------- Layer-1 attention: ONE WAVE PER ROW, NO DENSE FILL --------
// att_out is zeroed by a prior hipMemsetAsync (pure write stream at fill BW).
// This kernel is now a pure 256-MB adj read + sparse scatter + gather.
__global__ __launch_bounds__(256) void k_att1(const float* __restrict__ adj,
                                              const float* __restrict__ f1v,
                                              const float* __restrict__ f2v,
                                              const float* __restrict__ Wh1,
                                              float* __restrict__ att_out,
                                              float* __restrict__ h1,
                                              int* __restrict__ csr,
                                              int* __restrict__ degree) {
  __shared__ int   scols[4][MAXDEG];
  __shared__ float sval[4][MAXDEG];
  __shared__ int   cnt[4];
  const int tid = threadIdx.x;
  const int wid = tid >> 6, lane = tid & 63;
  const int row = blockIdx.x * 4 + wid;
  if (lane == 0) cnt[wid] = 0;
  __syncthreads();
  // Phase A: scan this wave's adjacency row (32 x float4 per lane, coalesced)
  const float4* arow = (const float4*)(adj + (size_t)row * NN);
  #pragma unroll 4
  for (int it = 0; it < 32; ++it) {
    float4 v = arow[it * 64 + lane];
    int base = (it * 64 + lane) * 4;
    if (v.x > 0.0f) { int s = atomicAdd(&cnt[wid], 1); if (s < MAXDEG) scols[wid][s] = base; }
    if (v.y > 0.0f) { int s = atomicAdd(&cnt[wid], 1); if (s < MAXDEG) scols[wid][s] = base + 1; }
    if (v.z > 0.0f) { int s = atomicAdd(&cnt[wid], 1); if (s < MAXDEG) scols[wid][s] = base + 2; }
    if (v.w > 0.0f) { int s = atomicAdd(&cnt[wid], 1); if (s < MAXDEG) scols[wid][s] = base + 3; }
  }
  __syncthreads();                               // publish scols/cnt (cross-lane via LDS)
  const int deg = min(cnt[wid], MAXDEG);
  if (lane == 0) degree[row] = deg;
  // Isolated row (deg==0): softmax over all-NEG_INF = uniform 1/N. Essentially
  // never taken for this data; kept for correctness.
  if (deg == 0) {
    float4 fv = make_float4(1.0f / NN, 1.0f / NN, 1.0f / NN, 1.0f / NN);
    float4* orow = (float4*)(att_out + (size_t)row * NN);
    #pragma unroll 8
    for (int it = 0; it < 32; ++it) orow[it * 64 + lane] = fv;
  }
  // CSR for layer 2
  for (int t = lane; t < deg; t += 64) csr[(size_t)row * MAXDEG + t] = scols[wid][t];
  // Phase B: softmax, up to 4 elements per lane, wave-wide shfl reductions
  const float f1r = f1v[row];
  float e[4]; int cols[4];
  float m = -3.0e38f;
  #pragma unroll
  for (int j = 0; j < 4; ++j) {
    int t = lane + j * 64;
    cols[j] = 0; e[j] = -3.0e38f;
    if (t < deg) {
      int c = scols[wid][t]; cols[j] = c;
      float x = f1r + f2v[c];
      e[j] = x > 0.0f ? x : 0.2f * x;
    }
    m = fmaxf(m, e[j]);
  }
  #pragma unroll
  for (int off = 32; off; off >>= 1) m = fmaxf(m, __shfl_xor(m, off));
  float ex[4]; float s = 0.0f;
  #pragma unroll
  for (int j = 0; j < 4; ++j) {
    ex[j] = __expf(e[j] - m);
    if (lane + j * 64 >= deg) ex[j] = 0.0f;
    s += ex[j];
  }
  #pragma unroll
  for (int off = 32; off; off >>= 1) s += __shfl_xor(s, off);
  const float inv = 1.0f / s;
  #pragma unroll
  for (int j = 0; j < 4; ++j) {
    int t = lane + j * 64;
    if (t < deg) {
      sval[wid][t] = ex[j] * inv;
      att_out[(size_t)row * NN + cols[j]] = ex[j] * inv;   // sparse scatter onto zeroed row
    }
  }
  __syncthreads();                               // publish sval (cross-lane via LDS)
  // Phase E: hp = att_row @ Wh1 (sparse). One wave owns the whole 128-wide row.
  float2 acc = make_float2(0.0f, 0.0f);
  if (deg > 0) {
    #pragma unroll 4
    for (int t = 0; t < deg; ++t) {
      float sv = sval[wid][t];
      float2 w = *(const float2*)(Wh1 + (size_t)scols[wid][t] * DHID + lane * 2);
      acc.x += sv * w.x; acc.y += sv * w.y;
    }
  } else {
    for (int r = 0; r < NN; ++r) {
      float2 w = *(const float2*)(Wh1 + (size_t)r * DHID + lane * 2);
      acc.x += w.x; acc.y += w.y;
    }
    acc.x *= (1.0f / (float)NN); acc.y *= (1.0f / (float)NN);
  }
  float hx = acc.x > 0.0f ? acc.x : (__expf(acc.x) - 1.0f);
  float hy = acc.y > 0.0f ? acc.y : (__expf(acc.y) - 1.0f);
  *(float2*)(h1 + (size_t)row * DHID + lane * 2) = make_float2(hx, hy);
}

// ---------------- Layer-2 attention: ONE WAVE PER ROW (reuses CSR) ----------
__global__ __launch_bounds__(256) void k_att2(const int* __restrict__ csr,
                                              const int* __restrict__ degree,
                                              const float* __restrict__ f1v,
                                              const float* __restrict__ f2v,
                                              const float* __restrict__ Wh2,
                                              float* __restrict__ h2) {
  __shared__ int   scols[4][MAXDEG];
  __shared__ float sval[4][MAXDEG];
  const int tid = threadIdx.x;
  const int wid = tid >> 6, lane = tid & 63;
  const int row = blockIdx.x * 4 + wid;
  const int deg = degree[row];
  const float f1r = f1v[row];
  float e[4]; int cols[4];
  float m = -3.0e38f;
  #pragma unroll
  for (int j = 0; j < 4; ++j) {
    int t = lane + j * 64;
    cols[j] = 0; e[j] = -3.0e38f;
    if (t < deg) {
      int c = csr[(size_t)row * MAXDEG + t];
      cols[j] = c; scols[wid][t] = c;
      float x = f1r + f2v[c];
      e[j] = x > 0.0f ? x : 0.2f * x;
    }
    m = fmaxf(m, e[j]);
  }
  #pragma unroll
  for (int off = 32; off; off >>= 1) m = fmaxf(m, __shfl_xor(m, off));
  float ex[4]; float s = 0.0f;
  #pragma unroll
  for (int j = 0; j < 4; ++j) {
    ex[j] = __expf(e[j] - m);
    if (lane + j * 64 >= deg) ex[j] = 0.0f;
    s += ex[j];
  }
  #pragma unroll
  for (int off = 32; off; off >>= 1) s += __shfl_xor(s, off);
  const float inv = 1.0f / s;
  #pragma unroll
  for (int j = 0; j < 4; ++j) { int t = lane + j * 64; if (t < deg) sval[wid][t] = ex[j] * inv; }
  __syncthreads();                               // publish scols/sval
  float acc = 0.0f;
  if (deg > 0) {
    #pragma unroll 4
    for (int t = 0; t < deg; ++t)
      acc += sval[wid][t] * Wh2[(size_t)scols[wid][t] * DOUT + lane];
  } else {
    for (int r = 0; r < NN; ++r) acc += Wh2[(size_t)r * DOUT + lane];
    acc *= (1.0f / (float)NN);
  }
  h2[(size_t)row * DOUT + lane] = acc;
}

// ---------------- genenet: sigmoid(h2 @ h2^T) * rowmask (bf16 MFMA) ---------
// Output stores are nontemporal: pure streaming 256-MB write, no L2 reuse.
__global__ __launch_bounds__(256) void k_genenet(const float* __restrict__ h2,
                                                 const int* __restrict__ degree,
                                                 float* __restrict__ out) {
  __shared__ __align__(16) unsigned short AB[2 * 128 * 64];   // 32 KB: As | Bs, reused as stage
  __shared__ float dmask[128];
  unsigned short* As = AB;
  unsigned short* Bs = AB + 128 * 64;
  const int tid = threadIdx.x;
  const int R0 = blockIdx.x * 128, C0 = blockIdx.y * 128;
  #pragma unroll
  for (int it = 0; it < 8; ++it) {
    int idx = it * 256 + tid;
    int r = idx >> 4, kq = idx & 15;
    int c = kq >> 1, hf = kq & 1;
    int off = r * 64 + (((c + r) & 7) << 3) + (hf << 2);   // in shorts, 8B-aligned
    float4 va = *(const float4*)(h2 + (size_t)(R0 + r) * DOUT + kq * 4);
    float4 vb = *(const float4*)(h2 + (size_t)(C0 + r) * DOUT + kq * 4);
    ushort4 ba = make_ushort4(f2bf(va.x), f2bf(va.y), f2bf(va.z), f2bf(va.w));
    ushort4 bb = make_ushort4(f2bf(vb.x), f2bf(vb.y), f2bf(vb.z), f2bf(vb.w));
    *(ushort4*)&As[off] = ba;
    *(ushort4*)&Bs[off] = bb;
  }
  if (tid < 128) dmask[tid] = (degree[R0 + tid] > 0) ? 1.0f : 0.0f;
  __syncthreads();
  const int wave = tid >> 6, lane = tid & 63;
  const int wr = wave >> 1, wc = wave & 1;     // 2x2 waves over 128x128 tile
  const int lr = lane & 15, quad = lane >> 4;
  short8 a[4][2], b[4][2];
  #pragma unroll
  for (int mi = 0; mi < 4; ++mi) {
    int r = wr * 64 + mi * 16 + lr;
    #pragma unroll
    for (int j = 0; j < 2; ++j) {
      int c = quad + 4 * j;
      a[mi][j] = *(const short8*)(const void*)&As[r * 64 + (((c + r) & 7) << 3)];
    }
  }
  #pragma unroll
  for (int ni = 0; ni < 4; ++ni) {
    int r = wc * 64 + ni * 16 + lr;
    #pragma unroll
    for (int j = 0; j < 2; ++j) {
      int c = quad + 4 * j;
      b[ni][j] = *(const short8*)(const void*)&Bs[r * 64 + (((c + r) & 7) << 3)];
    }
  }
  floatx4 acc[4][4] = {};
  #pragma unroll
  for (int mi = 0; mi < 4; ++mi)
    #pragma unroll
    for (int ni = 0; ni < 4; ++ni) {
      acc[mi][ni] = __builtin_amdgcn_mfma_f32_16x16x32_bf16(a[mi][0], b[ni][0], acc[mi][ni], 0, 0, 0);
      acc[mi][ni] = __builtin_amdgcn_mfma_f32_16x16x32_bf16(a[mi][1], b[ni][1], acc[mi][ni], 0, 0, 0);
    }
  __syncthreads();                 // everyone done reading As/Bs; safe to reuse as stage
  float* stage = (float*)AB;       // 64 rows x 128 cols fp32 (32 KB)
  #pragma unroll
  for (int half = 0; half < 2; ++half) {
    if (wr == half) {              // waves owning rows [half*64, half*64+64)
      #pragma unroll
      for (int mi = 0; mi < 4; ++mi)
        #pragma unroll
        for (int reg = 0; reg < 4; ++reg) {
          int lrow = mi * 16 + quad * 4 + reg;          // 0..63 within half
          #pragma unroll
          for (int ni = 0; ni < 4; ++ni)
            stage[lrow * 128 + wc * 64 + ni * 16 + lr] = acc[mi][ni][reg];
        }
    }
    __syncthreads();
    #pragma unroll
    for (int it = 0; it < 8; ++it) {
      int idx = it * 256 + tid;    // 0..2047
      int r = idx >> 5, c4 = idx & 31;                  // 32 threads stream one row
      float4 x = *(const float4*)&stage[r * 128 + c4 * 4];
      float msk = dmask[half * 64 + r];
      floatx4 o;
      o[0] = msk * __builtin_amdgcn_rcpf(1.0f + __expf(-x.x));
      o[1] = msk * __builtin_amdgcn_rcpf(1.0f + __expf(-x.y));
      o[2] = msk * __builtin_amdgcn_rcpf(1.0f + __expf(-x.z));
      o[3] = msk * __builtin_amdgcn_rcpf(1.0f + __expf(-x.w));
      __builtin_nontemporal_store(o, (floatx4*)(out + (size_t)(R0 + half * 64 + r) * NN + C0 + c4 * 4));
    }
    if (half == 0) __syncthreads();                     // before overwriting stage
  }
}

extern "C" void kernel_launch(void* const* d_in, const int* in_sizes, int n_in,
                              void* d_out, int out_size, void* d_ws, size_t ws_size,
                              hipStream_t stream) {
  const float* feat = (const float*)d_in[0];
  const float* adj  = (const float*)d_in[1];
  const float* W1   = (const float*)d_in[2];
  const float* a1   = (const float*)d_in[3];
  const float* W2   = (const float*)d_in[4];
  const float* a2   = (const float*)d_in[5];
  float* out = (float*)d_out;
  float* h2_out  = out;                               // [8192,64]
  float* gen_out = out + (size_t)NN * DOUT;           // [8192,8192]
  float* att_out = gen_out + (size_t)NN * NN;         // [8192,8192]
  // Big scratch lives inside gen_out: it is only written by the FINAL kernel,
  // and all readers of these intermediates run before it (stream-ordered).
  int*   csr  = (int*)gen_out;                        // 8192*256 ints (8 MB)
  float* Wh1  = gen_out + 2097152;                    // 4 MB
  float* h1   = gen_out + 3145728;                    // 4 MB
  float* Wh2  = gen_out + 4194304;                    // 2 MB
  float* f1_1 = gen_out + 4718592;
  float* f2_1 = f1_1 + NN;
  float* f1_2 = f2_1 + NN;
  float* f2_2 = f1_2 + NN;
  int* degree = (int*)d_ws;                           // 32 KB; survives to k_genenet

  // Zero att_out up front as a pure write stream (fillBuffer path runs at
  // ~6.3 TB/s); att1 then only scatters its ~82 nonzeros per row.
  (void)hipMemsetAsync((void*)att_out, 0, (size_t)NN * NN * sizeof(float), stream);

  k_gemm1  <<<dim3(NN / 32), dim3(256), 0, stream>>>(feat, W1, Wh1);
  k_fvec1  <<<dim3(NN / 4),  dim3(256), 0, stream>>>(Wh1, a1, f1_1, f2_1);
  k_att1   <<<dim3(NN / 4),  dim3(256), 0, stream>>>(adj, f1_1, f2_1, Wh1, att_out, h1, csr, degree);
  k_gemm2  <<<dim3(NN / 32), dim3(256), 0, stream>>>(h1, W2, Wh2);
  k_fvec2  <<<dim3(NN / 4),  dim3(256), 0, stream>>>(Wh2, a2, f1_2, f2_2);
  k_att2   <<<dim3(NN / 4),  dim3(256), 0, stream>>>(csr, degree, f1_2, f2_2, Wh2, h2_out);
  k_genenet<<<dim3(64, 64),  dim3(256), 0, stream>>>(h2_out, degree, gen_out);
}

// Round 6
// 787.227 us; speedup vs baseline: 1.0324x; 1.0142x over previous
//
#include <hip/hip_runtime.h>
#include <cstdint>
#include <cstddef>

#define NN 8192
#define DIN 256
#define DHID 128
#define DOUT 64
#define MAXDEG 256

using short8  = __attribute__((ext_vector_type(8))) short;
using floatx4 = __attribute__((ext_vector_type(4))) float;

__device__ inline unsigned short f2bf(float x) {
  union { float f; unsigned u; } c; c.f = x;
  unsigned r = (c.u + 0x7FFFu + ((c.u >> 16) & 1u)) >> 16;   // RNE
  return (unsigned short)r;
}

// ---------------- GEMM1 + fvec1 fused ---------------------------------------
// Wh1 = feat[8192,256] @ W1[256,128]; f1/f2 = Wh1 @ a1 halves, computed from
// the block-resident accumulators (rows never leave the block).
__global__ __launch_bounds__(256) void k_gemm1(const float* __restrict__ feat,
                                               const float* __restrict__ W1,
                                               const float* __restrict__ a1,
                                               float* __restrict__ Wh1,
                                               float* __restrict__ f1,
                                               float* __restrict__ f2) {
  __shared__ float Ws[64 * DHID];     // k-chunk x 128 cols (32 KB)
  __shared__ float Fs[32][65];        // 32 rows x 64 k (stride 65: conflict-free)
  const int tid = threadIdx.x;
  const int cx = tid & 31;            // cols cx*4..cx*4+3
  const int ry = tid >> 5;            // rows ry*4..ry*4+3
  const int r0 = blockIdx.x * 32;
  float acc[4][4] = {};
  for (int kc = 0; kc < DIN; kc += 64) {
    const float4* src = (const float4*)(W1 + (size_t)kc * DHID);
    float4* dst = (float4*)Ws;
    #pragma unroll
    for (int i = 0; i < 8; ++i) dst[i * 256 + tid] = src[i * 256 + tid];
    #pragma unroll
    for (int i = 0; i < 2; ++i) {
      int idx = i * 256 + tid;
      int row = idx >> 4, kq = idx & 15;
      float4 v = *(const float4*)(feat + (size_t)(r0 + row) * DIN + kc + kq * 4);
      Fs[row][kq * 4 + 0] = v.x; Fs[row][kq * 4 + 1] = v.y;
      Fs[row][kq * 4 + 2] = v.z; Fs[row][kq * 4 + 3] = v.w;
    }
    __syncthreads();
    #pragma unroll 4
    for (int k = 0; k < 64; ++k) {
      float4 w = *(const float4*)(Ws + k * DHID + cx * 4);
      #pragma unroll
      for (int r = 0; r < 4; ++r) {
        float f = Fs[ry * 4 + r][k];
        acc[r][0] += f * w.x; acc[r][1] += f * w.y;
        acc[r][2] += f * w.z; acc[r][3] += f * w.w;
      }
    }
    __syncthreads();
  }
  const float4 u = *(const float4*)(a1 + cx * 4);
  const float4 v = *(const float4*)(a1 + DHID + cx * 4);
  #pragma unroll
  for (int r = 0; r < 4; ++r) {
    float4 o = make_float4(acc[r][0], acc[r][1], acc[r][2], acc[r][3]);
    *(float4*)(Wh1 + (size_t)(r0 + ry * 4 + r) * DHID + cx * 4) = o;
    // fvec epilogue: reduce over the 32 cx-lanes of this half-wave
    float s1 = acc[r][0] * u.x + acc[r][1] * u.y + acc[r][2] * u.z + acc[r][3] * u.w;
    float s2 = acc[r][0] * v.x + acc[r][1] * v.y + acc[r][2] * v.z + acc[r][3] * v.w;
    #pragma unroll
    for (int off = 16; off; off >>= 1) { s1 += __shfl_xor(s1, off); s2 += __shfl_xor(s2, off); }
    if (cx == 0) { f1[r0 + ry * 4 + r] = s1; f2[r0 + ry * 4 + r] = s2; }
  }
}

// ---------------- GEMM2 + fvec2 fused ---------------------------------------
__global__ __launch_bounds__(256) void k_gemm2(const float* __restrict__ h1,
                                               const float* __restrict__ W2,
                                               const float* __restrict__ a2,
                                               float* __restrict__ Wh2,
                                               float* __restrict__ f1,
                                               float* __restrict__ f2) {
  __shared__ float Ws[64 * DOUT];     // 16 KB
  __shared__ float Fs[32][65];        // 8.3 KB
  const int tid = threadIdx.x;
  const int cx = tid & 15;            // cols cx*4
  const int ry = tid >> 4;            // rows ry*2 (0..15 -> 32 rows)
  const int r0 = blockIdx.x * 32;
  float acc[2][4] = {};
  for (int kc = 0; kc < DHID; kc += 64) {
    const float4* src = (const float4*)(W2 + (size_t)kc * DOUT);
    float4* dst = (float4*)Ws;
    #pragma unroll
    for (int i = 0; i < 4; ++i) dst[i * 256 + tid] = src[i * 256 + tid];
    #pragma unroll
    for (int i = 0; i < 2; ++i) {
      int idx = i * 256 + tid;
      int row = idx >> 4, kq = idx & 15;
      float4 v = *(const float4*)(h1 + (size_t)(r0 + row) * DHID + kc + kq * 4);
      Fs[row][kq * 4 + 0] = v.x; Fs[row][kq * 4 + 1] = v.y;
      Fs[row][kq * 4 + 2] = v.z; Fs[row][kq * 4 + 3] = v.w;
    }
    __syncthreads();
    #pragma unroll 4
    for (int k = 0; k < 64; ++k) {
      float4 w = *(const float4*)(Ws + k * DOUT + cx * 4);
      #pragma unroll
      for (int r = 0; r < 2; ++r) {
        float f = Fs[ry * 2 + r][k];
        acc[r][0] += f * w.x; acc[r][1] += f * w.y;
        acc[r][2] += f * w.z; acc[r][3] += f * w.w;
      }
    }
    __syncthreads();
  }
  const float4 u = *(const float4*)(a2 + cx * 4);
  const float4 v = *(const float4*)(a2 + DOUT + cx * 4);
  #pragma unroll
  for (int r = 0; r < 2; ++r) {
    float4 o = make_float4(acc[r][0], acc[r][1], acc[r][2], acc[r][3]);
    *(float4*)(Wh2 + (size_t)(r0 + ry * 2 + r) * DOUT + cx * 4) = o;
    float s1 = acc[r][0] * u.x + acc[r][1] * u.y + acc[r][2] * u.z + acc[r][3] * u.w;
    float s2 = acc[r][0] * v.x + acc[r][1] * v.y + acc[r][2] * v.z + acc[r][3] * v.w;
    #pragma unroll
    for (int off = 8; off; off >>= 1) { s1 += __shfl_xor(s1, off); s2 += __shfl_xor(s2, off); }
    if (cx == 0) { f1[r0 + ry * 2 + r] = s1; f2[r0 + ry * 2 + r] = s2; }
  }
}

// ---------------- Layer-1 attention: ONE WAVE PER ROW, IN-KERNEL DENSE WRITE
// Pass 1: read adj row, build nonzero bitmap (1 KB/row in LDS) + scols.
// Softmax over scols. Pass 2: stream the dense att row as nontemporal float4,
// computing p on the fly from the bitmap (no memset, no RMW scatter).
__global__ __launch_bounds__(256) void k_att1(const float* __restrict__ adj,
                                              const float* __restrict__ f1v,
                                              const float* __restrict__ f2v,
                                              const float* __restrict__ Wh1,
                                              float* __restrict__ att_out,
                                              float* __restrict__ h1,
                                              int* __restrict__ csr,
                                              int* __restrict__ degree) {
  __shared__ int      scols[4][MAXDEG];
  __shared__ float    sval[4][MAXDEG];
  __shared__ unsigned bitmap[4][NN / 32];   // 1 KB per row
  __shared__ int      cnt[4];
  const int tid = threadIdx.x;
  const int wid = tid >> 6, lane = tid & 63;
  const int row = blockIdx.x * 4 + wid;
  if (lane == 0) cnt[wid] = 0;
  __syncthreads();
  // Pass 1: scan adjacency row; bitmap nibble per float4, merged across 8 lanes
  const float4* arow = (const float4*)(adj + (size_t)row * NN);
  #pragma unroll 4
  for (int it = 0; it < 32; ++it) {
    float4 v = arow[it * 64 + lane];
    int base = (it * 64 + lane) * 4;
    unsigned nib = (v.x > 0.0f ? 1u : 0u) | (v.y > 0.0f ? 2u : 0u)
                 | (v.z > 0.0f ? 4u : 0u) | (v.w > 0.0f ? 8u : 0u);
    if (v.x > 0.0f) { int s = atomicAdd(&cnt[wid], 1); if (s < MAXDEG) scols[wid][s] = base; }
    if (v.y > 0.0f) { int s = atomicAdd(&cnt[wid], 1); if (s < MAXDEG) scols[wid][s] = base + 1; }
    if (v.z > 0.0f) { int s = atomicAdd(&cnt[wid], 1); if (s < MAXDEG) scols[wid][s] = base + 2; }
    if (v.w > 0.0f) { int s = atomicAdd(&cnt[wid], 1); if (s < MAXDEG) scols[wid][s] = base + 3; }
    unsigned wbits = nib << ((lane & 7) * 4);
    wbits |= __shfl_xor(wbits, 1);
    wbits |= __shfl_xor(wbits, 2);
    wbits |= __shfl_xor(wbits, 4);
    if ((lane & 7) == 0) bitmap[wid][it * 8 + (lane >> 3)] = wbits;
  }
  __syncthreads();                               // publish scols/cnt/bitmap
  const int deg = min(cnt[wid], MAXDEG);
  if (lane == 0) degree[row] = deg;
  // CSR for layer 2
  for (int t = lane; t < deg; t += 64) csr[(size_t)row * MAXDEG + t] = scols[wid][t];
  // Softmax over scols (up to 4 elements per lane, wave-wide shfl reductions)
  const float f1r = f1v[row];
  float e[4];
  float m = -3.0e38f;
  #pragma unroll
  for (int j = 0; j < 4; ++j) {
    int t = lane + j * 64;
    e[j] = -3.0e38f;
    if (t < deg) {
      int c = scols[wid][t];
      float x = f1r + f2v[c];
      e[j] = x > 0.0f ? x : 0.2f * x;
    }
    m = fmaxf(m, e[j]);
  }
  #pragma unroll
  for (int off = 32; off; off >>= 1) m = fmaxf(m, __shfl_xor(m, off));
  float ex[4]; float s = 0.0f;
  #pragma unroll
  for (int j = 0; j < 4; ++j) {
    ex[j] = __expf(e[j] - m);
    if (lane + j * 64 >= deg) ex[j] = 0.0f;
    s += ex[j];
  }
  #pragma unroll
  for (int off = 32; off; off >>= 1) s += __shfl_xor(s, off);
  const float inv = 1.0f / s;
  #pragma unroll
  for (int j = 0; j < 4; ++j) { int t = lane + j * 64; if (t < deg) sval[wid][t] = ex[j] * inv; }
  // Pass 2: dense nontemporal write with on-the-fly values from the bitmap
  const float fillv = (deg == 0) ? (1.0f / (float)NN) : 0.0f;
  floatx4* orow = (floatx4*)(att_out + (size_t)row * NN);
  for (int it = 0; it < 32; ++it) {
    unsigned wbits = bitmap[wid][it * 8 + (lane >> 3)];
    unsigned nib = (wbits >> ((lane & 7) * 4)) & 0xFu;
    int base = (it * 64 + lane) * 4;
    floatx4 o = {fillv, fillv, fillv, fillv};
    if (nib) {                                   // rare (~1% of chunks)
      #pragma unroll
      for (int k = 0; k < 4; ++k) {
        if (nib & (1u << k)) {
          float x = f1r + f2v[base + k];
          float ee = x > 0.0f ? x : 0.2f * x;
          o[k] = __expf(ee - m) * inv;
        }
      }
    }
    __builtin_nontemporal_store(o, orow + it * 64 + lane);
  }
  __syncthreads();                               // keep sval coherent across wave (safe)
  // Phase E: hp = att_row @ Wh1 (sparse). One wave owns the whole 128-wide row.
  float2 acc = make_float2(0.0f, 0.0f);
  if (deg > 0) {
    #pragma unroll 4
    for (int t = 0; t < deg; ++t) {
      float sv = sval[wid][t];
      float2 w = *(const float2*)(Wh1 + (size_t)scols[wid][t] * DHID + lane * 2);
      acc.x += sv * w.x; acc.y += sv * w.y;
    }
  } else {
    for (int r = 0; r < NN; ++r) {
      float2 w = *(const float2*)(Wh1 + (size_t)r * DHID + lane * 2);
      acc.x += w.x; acc.y += w.y;
    }
    acc.x *= (1.0f / (float)NN); acc.y *= (1.0f / (float)NN);
  }
  float hx = acc.x > 0.0f ? acc.x : (__expf(acc.x) - 1.0f);
  float hy = acc.y > 0.0f ? acc.y : (__expf(acc.y) - 1.0f);
  *(float2*)(h1 + (size_t)row * DHID + lane * 2) = make_float2(hx, hy);
}

// ---------------- Layer-2 attention: ONE WAVE PER ROW (reuses CSR) ----------
__global__ __launch_bounds__(256) void k_att2(const int* __restrict__ csr,
                                              const int* __restrict__ degree,
                                              const float* __restrict__ f1v,
                                              const float* __restrict__ f2v,
                                              const float* __restrict__ Wh2,
                                              float* __restrict__ h2) {
  __shared__ int   scols[4][MAXDEG];
  __shared__ float sval[4][MAXDEG];
  const int tid = threadIdx.x;
  const int wid = tid >> 6, lane = tid & 63;
  const int row = blockIdx.x * 4 + wid;
  const int deg = degree[row];
  const float f1r = f1v[row];
  float e[4];
  float m = -3.0e38f;
  #pragma unroll
  for (int j = 0; j < 4; ++j) {
    int t = lane + j * 64;
    e[j] = -3.0e38f;
    if (t < deg) {
      int c = csr[(size_t)row * MAXDEG + t];
      scols[wid][t] = c;
      float x = f1r + f2v[c];
      e[j] = x > 0.0f ? x : 0.2f * x;
    }
    m = fmaxf(m, e[j]);
  }
  #pragma unroll
  for (int off = 32; off; off >>= 1) m = fmaxf(m, __shfl_xor(m, off));
  float ex[4]; float s = 0.0f;
  #pragma unroll
  for (int j = 0; j < 4; ++j) {
    ex[j] = __expf(e[j] - m);
    if (lane + j * 64 >= deg) ex[j] = 0.0f;
    s += ex[j];
  }
  #pragma unroll
  for (int off = 32; off; off >>= 1) s += __shfl_xor(s, off);
  const float inv = 1.0f / s;
  #pragma unroll
  for (int j = 0; j < 4; ++j) { int t = lane + j * 64; if (t < deg) sval[wid][t] = ex[j] * inv; }
  __syncthreads();                               // publish scols/sval
  float acc = 0.0f;
  if (deg > 0) {
    #pragma unroll 4
    for (int t = 0; t < deg; ++t)
      acc += sval[wid][t] * Wh2[(size_t)scols[wid][t] * DOUT + lane];
  } else {
    for (int r = 0; r < NN; ++r) acc += Wh2[(size_t)r * DOUT + lane];
    acc *= (1.0f / (float)NN);
  }
  h2[(size_t)row * DOUT + lane] = acc;
}

// ---------------- genenet: sigmoid(h2 @ h2^T) * rowmask (bf16 MFMA) ---------
__global__ __launch_bounds__(256) void k_genenet(const float* __restrict__ h2,
                                                 const int* __restrict__ degree,
                                                 float* __restrict__ out) {
  __shared__ __align__(16) unsigned short AB[2 * 128 * 64];   // 32 KB: As | Bs, reused as stage
  __shared__ float dmask[128];
  unsigned short* As = AB;
  unsigned short* Bs = AB + 128 * 64;
  const int tid = threadIdx.x;
  const int R0 = blockIdx.x * 128, C0 = blockIdx.y * 128;
  #pragma unroll
  for (int it = 0; it < 8; ++it) {
    int idx = it * 256 + tid;
    int r = idx >> 4, kq = idx & 15;
    int c = kq >> 1, hf = kq & 1;
    int off = r * 64 + (((c + r) & 7) << 3) + (hf << 2);   // in shorts, 8B-aligned
    float4 va = *(const float4*)(h2 + (size_t)(R0 + r) * DOUT + kq * 4);
    float4 vb = *(const float4*)(h2 + (size_t)(C0 + r) * DOUT + kq * 4);
    ushort4 ba = make_ushort4(f2bf(va.x), f2bf(va.y), f2bf(va.z), f2bf(va.w));
    ushort4 bb = make_ushort4(f2bf(vb.x), f2bf(vb.y), f2bf(vb.z), f2bf(vb.w));
    *(ushort4*)&As[off] = ba;
    *(ushort4*)&Bs[off] = bb;
  }
  if (tid < 128) dmask[tid] = (degree[R0 + tid] > 0) ? 1.0f : 0.0f;
  __syncthreads();
  const int wave = tid >> 6, lane = tid & 63;
  const int wr = wave >> 1, wc = wave & 1;     // 2x2 waves over 128x128 tile
  const int lr = lane & 15, quad = lane >> 4;
  short8 a[4][2], b[4][2];
  #pragma unroll
  for (int mi = 0; mi < 4; ++mi) {
    int r = wr * 64 + mi * 16 + lr;
    #pragma unroll
    for (int j = 0; j < 2; ++j) {
      int c = quad + 4 * j;
      a[mi][j] = *(const short8*)(const void*)&As[r * 64 + (((c + r) & 7) << 3)];
    }
  }
  #pragma unroll
  for (int ni = 0; ni < 4; ++ni) {
    int r = wc * 64 + ni * 16 + lr;
    #pragma unroll
    for (int j = 0; j < 2; ++j) {
      int c = quad + 4 * j;
      b[ni][j] = *(const short8*)(const void*)&Bs[r * 64 + (((c + r) & 7) << 3)];
    }
  }
  floatx4 acc[4][4] = {};
  #pragma unroll
  for (int mi = 0; mi < 4; ++mi)
    #pragma unroll
    for (int ni = 0; ni < 4; ++ni) {
      acc[mi][ni] = __builtin_amdgcn_mfma_f32_16x16x32_bf16(a[mi][0], b[ni][0], acc[mi][ni], 0, 0, 0);
      acc[mi][ni] = __builtin_amdgcn_mfma_f32_16x16x32_bf16(a[mi][1], b[ni][1], acc[mi][ni], 0, 0, 0);
    }
  __syncthreads();                 // everyone done reading As/Bs; safe to reuse as stage
  float* stage = (float*)AB;       // 64 rows x 128 cols fp32 (32 KB)
  #pragma unroll
  for (int half = 0; half < 2; ++half) {
    if (wr == half) {              // waves owning rows [half*64, half*64+64)
      #pragma unroll
      for (int mi = 0; mi < 4; ++mi)
        #pragma unroll
        for (int reg = 0; reg < 4; ++reg) {
          int lrow = mi * 16 + quad * 4 + reg;          // 0..63 within half
          #pragma unroll
          for (int ni = 0; ni < 4; ++ni)
            stage[lrow * 128 + wc * 64 + ni * 16 + lr] = acc[mi][ni][reg];
        }
    }
    __syncthreads();
    #pragma unroll
    for (int it = 0; it < 8; ++it) {
      int idx = it * 256 + tid;    // 0..2047
      int r = idx >> 5, c4 = idx & 31;                  // 32 threads stream one row
      float4 x = *(const float4*)&stage[r * 128 + c4 * 4];
      float msk = dmask[half * 64 + r];
      floatx4 o;
      o[0] = msk * __builtin_amdgcn_rcpf(1.0f + __expf(-x.x));
      o[1] = msk * __builtin_amdgcn_rcpf(1.0f + __expf(-x.y));
      o[2] = msk * __builtin_amdgcn_rcpf(1.0f + __expf(-x.z));
      o[3] = msk * __builtin_amdgcn_rcpf(1.0f + __expf(-x.w));
      __builtin_nontemporal_store(o, (floatx4*)(out + (size_t)(R0 + half * 64 + r) * NN + C0 + c4 * 4));
    }
    if (half == 0) __syncthreads();                     // before overwriting stage
  }
}

extern "C" void kernel_launch(void* const* d_in, const int* in_sizes, int n_in,
                              void* d_out, int out_size, void* d_ws, size_t ws_size,
                              hipStream_t stream) {
  const float* feat = (const float*)d_in[0];
  const float* adj  = (const float*)d_in[1];
  const float* W1   = (const float*)d_in[2];
  const float* a1   = (const float*)d_in[3];
  const float* W2   = (const float*)d_in[4];
  const float* a2   = (const float*)d_in[5];
  float* out = (float*)d_out;
  float* h2_out  = out;                               // [8192,64]
  float* gen_out = out + (size_t)NN * DOUT;           // [8192,8192]
  float* att_out = gen_out + (size_t)NN * NN;         // [8192,8192]
  // Big scratch lives inside gen_out: it is only written by the FINAL kernel,
  // and all readers of these intermediates run before it (stream-ordered).
  int*   csr  = (int*)gen_out;                        // 8192*256 ints (8 MB)
  float* Wh1  = gen_out + 2097152;                    // 4 MB
  float* h1   = gen_out + 3145728;                    // 4 MB
  float* Wh2  = gen_out + 4194304;                    // 2 MB
  float* f1_1 = gen_out + 4718592;
  float* f2_1 = f1_1 + NN;
  float* f1_2 = f2_1 + NN;
  float* f2_2 = f1_2 + NN;
  int* degree = (int*)d_ws;                           // 32 KB; survives to k_genenet

  k_gemm1  <<<dim3(NN / 32), dim3(256), 0, stream>>>(feat, W1, a1, Wh1, f1_1, f2_1);
  k_att1   <<<dim3(NN / 4),  dim3(256), 0, stream>>>(adj, f1_1, f2_1, Wh1, att_out, h1, csr, degree);
  k_gemm2  <<<dim3(NN / 32), dim3(256), 0, stream>>>(h1, W2, a2, Wh2, f1_2, f2_2);
  k_att2   <<<dim3(NN / 4),  dim3(256), 0, stream>>>(csr, degree, f1_2, f2_2, Wh2, h2_out);
  k_genenet<<<dim3(64, 64),  dim3(256), 0, stream>>>(h2_out, degree, gen_out);
}